// Round 1
// baseline (859.723 us; speedup 1.0000x reference)
//
#include <hip/hip_runtime.h>
#include <math.h>

namespace {
constexpr int V = 50000, E = 256, H = 512, S = 500, B = 64, OOVN = 50;
constexpr int VEXT = V + OOVN;   // 50050
constexpr int CCAT = E + 3 * H;  // 1792  (embed | h_new | context)
constexpr int G3 = 3 * H;        // 1536
// GRU x = [embed(0:256), context(256:1280)]; context lives at CCAT offset 768.

__device__ __forceinline__ float wsum(float v) {
#pragma unroll
  for (int off = 32; off > 0; off >>= 1) v += __shfl_xor(v, off, 64);
  return v;
}
__device__ __forceinline__ float sigmoidf(float x) { return 1.f / (1.f + __expf(-x)); }
__device__ __forceinline__ void smerge(float& m, float& l, float om, float ol) {
  float nm = fmaxf(m, om);
  l = l * __expf(m - nm) + ol * __expf(om - nm);
  m = nm;
}

// ---- embed gather: concat[b][0:256] = emb[token[b]] ----
__global__ void k_embed(const int* __restrict__ tok, const float* __restrict__ emb,
                        float* __restrict__ cc) {
  int b = blockIdx.x, t = threadIdx.x;  // 64 threads
  int token = tok[b];
  const float4 v = *reinterpret_cast<const float4*>(&emb[token * E + t * 4]);
  *reinterpret_cast<float4*>(&cc[b * CCAT + t * 4]) = v;
}

// ---- q[b][o] = sum_h prev[b][h] * Wq[o][h]; lane=b, 8 rows/wave ----
__global__ void k_q(const float* __restrict__ prevh, const float* __restrict__ Wq,
                    float* __restrict__ q) {
  int lane = threadIdx.x & 63;
  int gw = blockIdx.x * 4 + (threadIdx.x >> 6);  // 0..63
  int o0 = gw * 8;
  float acc[8];
#pragma unroll
  for (int j = 0; j < 8; ++j) acc[j] = 0.f;
  const float* xr = prevh + lane * H;
  for (int k = 0; k < H; k += 4) {
    float4 xv = *reinterpret_cast<const float4*>(&xr[k]);
#pragma unroll
    for (int j = 0; j < 8; ++j) {
      float4 wv = *reinterpret_cast<const float4*>(&Wq[(o0 + j) * H + k]);
      acc[j] += xv.x * wv.x + xv.y * wv.y + xv.z * wv.z + xv.w * wv.w;
    }
  }
#pragma unroll
  for (int j = 0; j < 8; ++j) q[lane * H + o0 + j] = acc[j];
}

// ---- scores[s][b] = sum_h tanh(q[b][h]+pk[s][b][h]) * We[h]; wave per (s,b) ----
__global__ void k_scores(const float* __restrict__ q, const float* __restrict__ pk,
                         const float* __restrict__ We, float* __restrict__ scores) {
  int lane = threadIdx.x & 63;
  int gw = blockIdx.x * 4 + (threadIdx.x >> 6);  // 0..31999
  int s = gw >> 6, b = gw & 63;
  const float* qr = q + b * H + lane * 8;
  const float* kr = pk + ((size_t)s * B + b) * H + lane * 8;
  const float* er = We + lane * 8;
  float part = 0.f;
#pragma unroll
  for (int i = 0; i < 2; ++i) {
    float4 qv = *reinterpret_cast<const float4*>(qr + i * 4);
    float4 kv = *reinterpret_cast<const float4*>(kr + i * 4);
    float4 ev = *reinterpret_cast<const float4*>(er + i * 4);
    part += tanhf(qv.x + kv.x) * ev.x + tanhf(qv.y + kv.y) * ev.y +
            tanhf(qv.z + kv.z) * ev.z + tanhf(qv.w + kv.w) * ev.w;
  }
  part = wsum(part);
  if (lane == 0) scores[s * B + b] = part;
}

// ---- column softmax over s; write alphas[S][B] and alphasT[B][S] ----
__global__ void k_softmax_s(const float* __restrict__ scores, float* __restrict__ alphas,
                            float* __restrict__ alphasT) {
  int b = blockIdx.x, t = threadIdx.x;  // 512 threads
  int w = t >> 6, lane = t & 63;
  __shared__ float rm[8], rl[8];
  float v = (t < S) ? scores[t * B + b] : -INFINITY;
  float m = v;
#pragma unroll
  for (int off = 32; off > 0; off >>= 1) m = fmaxf(m, __shfl_xor(m, off, 64));
  if (lane == 0) rm[w] = m;
  __syncthreads();
  float bm = rm[0];
#pragma unroll
  for (int i = 1; i < 8; ++i) bm = fmaxf(bm, rm[i]);
  float e = (t < S) ? __expf(v - bm) : 0.f;
  float sw = wsum(e);
  if (lane == 0) rl[w] = sw;
  __syncthreads();
  float tot = rl[0];
#pragma unroll
  for (int i = 1; i < 8; ++i) tot += rl[i];
  if (t < S) {
    float a = e / tot;
    alphas[t * B + b] = a;
    alphasT[b * S + t] = a;
  }
}

// ---- context partials: part[c][b][0:1024] = sum_{s in chunk} alphas[s][b]*ench[s][b][:] ----
__global__ void k_ctx_part(const float* __restrict__ alphas, const float* __restrict__ ench,
                           float* __restrict__ part) {
  int b = blockIdx.x, c = blockIdx.y, t = threadIdx.x;  // 256 threads, float4 over 1024
  float ax = 0.f, ay = 0.f, az = 0.f, aw = 0.f;
#pragma unroll 2
  for (int s = c * 50; s < c * 50 + 50; ++s) {
    float a = alphas[s * B + b];
    float4 v = *reinterpret_cast<const float4*>(&ench[(((size_t)s * B) + b) * 1024 + t * 4]);
    ax += a * v.x; ay += a * v.y; az += a * v.z; aw += a * v.w;
  }
  float4 o; o.x = ax; o.y = ay; o.z = az; o.w = aw;
  *reinterpret_cast<float4*>(&part[((c * B) + b) * 1024 + t * 4]) = o;
}

// ---- combine context partials into concat[b][768:1792] ----
__global__ void k_ctx_sum(const float* __restrict__ part, float* __restrict__ cc) {
  int b = blockIdx.x, t = threadIdx.x;  // 256 threads
  float ax = 0.f, ay = 0.f, az = 0.f, aw = 0.f;
#pragma unroll
  for (int c = 0; c < 10; ++c) {
    float4 v = *reinterpret_cast<const float4*>(&part[((c * B) + b) * 1024 + t * 4]);
    ax += v.x; ay += v.y; az += v.z; aw += v.w;
  }
  float4 o; o.x = ax; o.y = ay; o.z = az; o.w = aw;
  *reinterpret_cast<float4*>(&cc[b * CCAT + 768 + t * 4]) = o;
}

// ---- GRU matmuls: gi[b][j]=bih[j]+x.Wih[j], gh[b][j]=bhh[j]+h.Whh[j]; lane=b, 8 rows/wave ----
__global__ void k_gru_mm(const float* __restrict__ cc, const float* __restrict__ prevh,
                         const float* __restrict__ Wih, const float* __restrict__ Whh,
                         const float* __restrict__ bih, const float* __restrict__ bhh,
                         float* __restrict__ gi, float* __restrict__ gh) {
  int lane = threadIdx.x & 63;
  int gw = blockIdx.x * 4 + (threadIdx.x >> 6);  // 0..191
  int j0 = gw * 8;
  float accA[8], accB[8];
#pragma unroll
  for (int j = 0; j < 8; ++j) { accA[j] = bih[j0 + j]; accB[j] = bhh[j0 + j]; }
  const float* cr = cc + lane * CCAT;
  // x part 1: embed (x_k = cc[k], k<256)
  for (int k = 0; k < 256; k += 4) {
    float4 xv = *reinterpret_cast<const float4*>(&cr[k]);
#pragma unroll
    for (int j = 0; j < 8; ++j) {
      float4 wv = *reinterpret_cast<const float4*>(&Wih[(j0 + j) * 1280 + k]);
      accA[j] += xv.x * wv.x + xv.y * wv.y + xv.z * wv.z + xv.w * wv.w;
    }
  }
  // x part 2: context (x_k = cc[k+512], 256<=k<1280)
  for (int k = 256; k < 1280; k += 4) {
    float4 xv = *reinterpret_cast<const float4*>(&cr[k + 512]);
#pragma unroll
    for (int j = 0; j < 8; ++j) {
      float4 wv = *reinterpret_cast<const float4*>(&Wih[(j0 + j) * 1280 + k]);
      accA[j] += xv.x * wv.x + xv.y * wv.y + xv.z * wv.z + xv.w * wv.w;
    }
  }
  const float* hr = prevh + lane * H;
  for (int k = 0; k < 512; k += 4) {
    float4 hv = *reinterpret_cast<const float4*>(&hr[k]);
#pragma unroll
    for (int j = 0; j < 8; ++j) {
      float4 wv = *reinterpret_cast<const float4*>(&Whh[(j0 + j) * 512 + k]);
      accB[j] += hv.x * wv.x + hv.y * wv.y + hv.z * wv.z + hv.w * wv.w;
    }
  }
#pragma unroll
  for (int j = 0; j < 8; ++j) {
    gi[lane * G3 + j0 + j] = accA[j];
    gh[lane * G3 + j0 + j] = accB[j];
  }
}

// ---- GRU gates -> h_new into concat[b][256:768] and d_out hidden region ----
__global__ void k_gates(const float* __restrict__ gi, const float* __restrict__ gh,
                        const float* __restrict__ prevh, float* __restrict__ cc,
                        float* __restrict__ hout) {
  int idx = blockIdx.x * 256 + threadIdx.x;  // B*H = 32768
  int b = idx >> 9, j = idx & 511;
  float ir = gi[b * G3 + j],        hr = gh[b * G3 + j];
  float iz = gi[b * G3 + 512 + j],  hz = gh[b * G3 + 512 + j];
  float in_ = gi[b * G3 + 1024 + j], hn = gh[b * G3 + 1024 + j];
  float r = sigmoidf(ir + hr);
  float z = sigmoidf(iz + hz);
  float n = tanhf(in_ + r * hn);
  float h = prevh[b * H + j];
  float hnew = (1.f - z) * n + z * h;
  cc[b * CCAT + E + j] = hnew;
  hout[b * H + j] = hnew;
}

// ---- lin[b][o] = linb[o] + concat.linW[o]; plus pgsum[b]; lane=b ----
__global__ void k_linpg(const float* __restrict__ cc, const float* __restrict__ linW,
                        const float* __restrict__ linb, const float* __restrict__ pgW,
                        const float* __restrict__ pgb, float* __restrict__ lin,
                        float* __restrict__ pgsum) {
  int lane = threadIdx.x & 63;
  int gw = blockIdx.x * 4 + (threadIdx.x >> 6);
  const float* cr = cc + lane * CCAT;
  if (gw < 64) {
    int o0 = gw * 8;
    float acc[8];
#pragma unroll
    for (int j = 0; j < 8; ++j) acc[j] = linb[o0 + j];
    for (int k = 0; k < CCAT; k += 4) {
      float4 xv = *reinterpret_cast<const float4*>(&cr[k]);
#pragma unroll
      for (int j = 0; j < 8; ++j) {
        float4 wv = *reinterpret_cast<const float4*>(&linW[(o0 + j) * CCAT + k]);
        acc[j] += xv.x * wv.x + xv.y * wv.y + xv.z * wv.z + xv.w * wv.w;
      }
    }
#pragma unroll
    for (int j = 0; j < 8; ++j) lin[lane * H + o0 + j] = acc[j];
  } else if (gw == 64) {
    float acc = pgb[0];
    for (int k = 0; k < CCAT; k += 4) {
      float4 xv = *reinterpret_cast<const float4*>(&cr[k]);
      float4 wv = *reinterpret_cast<const float4*>(&pgW[k]);
      acc += xv.x * wv.x + xv.y * wv.y + xv.z * wv.z + xv.w * wv.w;
    }
    pgsum[lane] = acc;
  }
}

// ---- logits[b][v] = outb[v] + lin[b].outW[v]; lane=b, 8 rows/wave ----
__global__ void k_logits(const float* __restrict__ lin, const float* __restrict__ outW,
                         const float* __restrict__ outb, float* __restrict__ logits) {
  int lane = threadIdx.x & 63;
  int gw = blockIdx.x * 4 + (threadIdx.x >> 6);
  if (gw >= 6250) return;
  int v0 = gw * 8;
  float acc[8];
#pragma unroll
  for (int j = 0; j < 8; ++j) acc[j] = outb[v0 + j];
  const float* lr = lin + lane * H;
  for (int k = 0; k < H; k += 4) {
    float4 xv = *reinterpret_cast<const float4*>(&lr[k]);
#pragma unroll
    for (int j = 0; j < 8; ++j) {
      float4 wv = *reinterpret_cast<const float4*>(&outW[(v0 + j) * H + k]);
      acc[j] += xv.x * wv.x + xv.y * wv.y + xv.z * wv.z + xv.w * wv.w;
    }
  }
  float* orow = logits + (size_t)lane * V + v0;
  float4 o0v; o0v.x = acc[0]; o0v.y = acc[1]; o0v.z = acc[2]; o0v.w = acc[3];
  float4 o1v; o1v.x = acc[4]; o1v.y = acc[5]; o1v.z = acc[6]; o1v.w = acc[7];
  *reinterpret_cast<float4*>(orow) = o0v;
  *reinterpret_cast<float4*>(orow + 4) = o1v;
}

// ---- online softmax partials over V (chunks of 5000) ----
__global__ void k_vmax(const float* __restrict__ logits, float* __restrict__ pm,
                       float* __restrict__ pl) {
  int b = blockIdx.x, c = blockIdx.y, t = threadIdx.x;
  const float* row = logits + (size_t)b * V + c * 5000;
  float m = -INFINITY, l = 0.f;
  for (int i = t; i < 1250; i += 256) {
    float4 v = *reinterpret_cast<const float4*>(&row[i * 4]);
    float mm = fmaxf(fmaxf(v.x, v.y), fmaxf(v.z, v.w));
    float nm = fmaxf(m, mm);
    l = l * __expf(m - nm) + __expf(v.x - nm) + __expf(v.y - nm) + __expf(v.z - nm) +
        __expf(v.w - nm);
    m = nm;
  }
#pragma unroll
  for (int off = 32; off > 0; off >>= 1) {
    float om = __shfl_xor(m, off, 64), ol = __shfl_xor(l, off, 64);
    smerge(m, l, om, ol);
  }
  __shared__ float sm[4], sl[4];
  int w = t >> 6, lane = t & 63;
  if (lane == 0) { sm[w] = m; sl[w] = l; }
  __syncthreads();
  if (t == 0) {
#pragma unroll
    for (int i = 1; i < 4; ++i) smerge(m, l, sm[i], sl[i]);
    pm[b * 10 + c] = m;
    pl[b * 10 + c] = l;
  }
}

// ---- ext init: d_out[b][v] = pg*softmax + 1e-12 (v<V), 1e-12 for OOV tail ----
__global__ void k_extinit(const float* __restrict__ logits, const float* __restrict__ pm,
                          const float* __restrict__ pl, const float* __restrict__ pgsum,
                          float* __restrict__ out) {
  int b = blockIdx.x, c = blockIdx.y, t = threadIdx.x;
  float m = -INFINITY, l = 0.f;
#pragma unroll
  for (int i = 0; i < 10; ++i) smerge(m, l, pm[b * 10 + i], pl[b * 10 + i]);
  float pg = sigmoidf(pgsum[b]);
  float scale = pg / l;
  const float* lr = logits + (size_t)b * V + c * 5000;
  float* orow = out + (size_t)b * VEXT + c * 5000;
  for (int i = t; i < 2500; i += 256) {
    float2 v = *reinterpret_cast<const float2*>(&lr[i * 2]);
    float2 r;
    r.x = scale * __expf(v.x - m) + 1e-12f;
    r.y = scale * __expf(v.y - m) + 1e-12f;
    *reinterpret_cast<float2*>(&orow[i * 2]) = r;
  }
  if (c == 9 && t < OOVN) out[(size_t)b * VEXT + V + t] = 1e-12f;
}

// ---- pointer scatter: out[b][extv[b][s]] += (1-pg)*alphasT[b][s] ----
__global__ void k_scatter(const int* __restrict__ extv, const float* __restrict__ alphasT,
                          const float* __restrict__ pgsum, float* __restrict__ out) {
  int b = blockIdx.x, t = threadIdx.x;  // 512 threads
  if (t >= S) return;
  float pg = sigmoidf(pgsum[b]);
  float wgt = (1.f - pg) * alphasT[b * S + t];
  int idx = extv[b * S + t];
  atomicAdd(&out[(size_t)b * VEXT + idx], wgt);
}

// ---- in-place log of the prob region ----
__global__ void k_log(float* __restrict__ out) {
  constexpr int n2 = B * VEXT / 2;  // 1,601,600 float2s
  float2* p = reinterpret_cast<float2*>(out);
  for (int i = blockIdx.x * blockDim.x + threadIdx.x; i < n2; i += gridDim.x * blockDim.x) {
    float2 v = p[i];
    v.x = logf(v.x);
    v.y = logf(v.y);
    p[i] = v;
  }
}
}  // namespace

extern "C" void kernel_launch(void* const* d_in, const int* in_sizes, int n_in,
                              void* d_out, int out_size, void* d_ws, size_t ws_size,
                              hipStream_t stream) {
  const int*   tok   = (const int*)d_in[0];
  const float* ench  = (const float*)d_in[1];
  const float* pk    = (const float*)d_in[2];
  // d_in[3] src_mask: unused (reference ignores it)
  const float* prevh = (const float*)d_in[4];
  const int*   extv  = (const int*)d_in[5];
  // d_in[6] batch_max_oov == 50 (compile-time constant here)
  const float* emb   = (const float*)d_in[7];
  const float* Wq    = (const float*)d_in[8];
  const float* We    = (const float*)d_in[9];
  const float* Wih   = (const float*)d_in[10];
  const float* Whh   = (const float*)d_in[11];
  const float* bih   = (const float*)d_in[12];
  const float* bhh   = (const float*)d_in[13];
  const float* linW  = (const float*)d_in[14];
  const float* linb  = (const float*)d_in[15];
  const float* pgW   = (const float*)d_in[16];
  const float* pgb   = (const float*)d_in[17];
  const float* outW  = (const float*)d_in[18];
  const float* outb  = (const float*)d_in[19];

  float* out = (float*)d_out;
  float* ws = (float*)d_ws;

  float* q       = ws;                  // 32768
  float* scores  = q + 32768;           // 32000
  float* alphas  = scores + 32000;      // 32000
  float* alphasT = alphas + 32000;      // 32000
  float* ctxp    = alphasT + 32000;     // 10*64*1024 = 655360
  float* cc      = ctxp + 655360;       // 64*1792 = 114688
  float* gi      = cc + 114688;         // 64*1536 = 98304
  float* gh      = gi + 98304;          // 98304
  float* linv    = gh + 98304;          // 32768
  float* pgsum   = linv + 32768;        // 64
  float* logits  = pgsum + 64;          // 64*50000 = 3200000
  float* pm      = logits + 3200000;    // 640
  float* pl      = pm + 640;            // 640
  float* hout    = out + (size_t)B * VEXT;

  k_embed<<<dim3(B), dim3(64), 0, stream>>>(tok, emb, cc);
  k_q<<<dim3(16), dim3(256), 0, stream>>>(prevh, Wq, q);
  k_scores<<<dim3(8000), dim3(256), 0, stream>>>(q, pk, We, scores);
  k_softmax_s<<<dim3(B), dim3(512), 0, stream>>>(scores, alphas, alphasT);
  k_ctx_part<<<dim3(B, 10), dim3(256), 0, stream>>>(alphas, ench, ctxp);
  k_ctx_sum<<<dim3(B), dim3(256), 0, stream>>>(ctxp, cc);
  k_gru_mm<<<dim3(48), dim3(256), 0, stream>>>(cc, prevh, Wih, Whh, bih, bhh, gi, gh);
  k_gates<<<dim3(128), dim3(256), 0, stream>>>(gi, gh, prevh, cc, hout);
  k_linpg<<<dim3(17), dim3(256), 0, stream>>>(cc, linW, linb, pgW, pgb, linv, pgsum);
  k_logits<<<dim3(1563), dim3(256), 0, stream>>>(linv, outW, outb, logits);
  k_vmax<<<dim3(B, 10), dim3(256), 0, stream>>>(logits, pm, pl);
  k_extinit<<<dim3(B, 10), dim3(256), 0, stream>>>(logits, pm, pl, pgsum, out);
  k_scatter<<<dim3(B), dim3(512), 0, stream>>>(extv, alphasT, pgsum, out);
  k_log<<<dim3(2048), dim3(256), 0, stream>>>(out);
}

// Round 2
// 222.979 us; speedup vs baseline: 3.8556x; 3.8556x over previous
//
#include <hip/hip_runtime.h>
#include <hip/hip_bf16.h>
#include <math.h>

namespace {
constexpr int V = 50000, E = 256, H = 512, S = 500, B = 64, OOVN = 50;
constexpr int VEXT = V + OOVN;   // 50050
constexpr int CCAT = E + 3 * H;  // 1792  (embed | h_new | context)
constexpr int G3 = 3 * H;        // 1536

typedef __attribute__((ext_vector_type(8))) short short8;
typedef __attribute__((ext_vector_type(4))) float f32x4;

__device__ __forceinline__ float wsum(float v) {
#pragma unroll
  for (int off = 32; off > 0; off >>= 1) v += __shfl_xor(v, off, 64);
  return v;
}
__device__ __forceinline__ float sigmoidf(float x) { return 1.f / (1.f + __expf(-x)); }
__device__ __forceinline__ void smerge(float& m, float& l, float om, float ol) {
  float nm = fmaxf(m, om);
  l = l * __expf(m - nm) + ol * __expf(om - nm);
  m = nm;
}

__device__ __forceinline__ short bf16_rn_s(float f) {
  __hip_bfloat16 h = __float2bfloat16(f);
  return __builtin_bit_cast(short, h);
}
// split f into hi (bf16 truncate) + lo (bf16 rounded residual); f ~= hi + lo
__device__ __forceinline__ void hilo1(float f, short* hi, short* lo) {
  unsigned u = __float_as_uint(f);
  *hi = (short)(u >> 16);
  *lo = bf16_rn_s(f - __uint_as_float(u & 0xffff0000u));
}
__device__ __forceinline__ void hilo8(float4 a, float4 b, short8& hi, short8& lo) {
  float f[8] = {a.x, a.y, a.z, a.w, b.x, b.y, b.z, b.w};
#pragma unroll
  for (int i = 0; i < 8; ++i) {
    unsigned u = __float_as_uint(f[i]);
    hi[i] = (short)(u >> 16);
    lo[i] = bf16_rn_s(f[i] - __uint_as_float(u & 0xffff0000u));
  }
}

// ---- MFMA core: one wave computes C[0:64][n0:n0+16] partial over a K-chunk ----
// X (bf16 hi/lo, row-major [64][ldx]) starting at col xk0; W fp32 [N][ldw] from col wk0.
// ksteps 32-wide K steps. Writes (not accumulates) C[64][ldc]; adds bias if non-null.
// MFMA 16x16x32 bf16 layouts (m89-verified): A row=l&15,k=(l>>4)*8+j ;
// B col=l&15,k=(l>>4)*8+j ; D col=l&15,row=(l>>4)*4+r.
__device__ __forceinline__ void gemm16(const short* __restrict__ Xhi,
                                       const short* __restrict__ Xlo, int ldx, int xk0,
                                       const float* __restrict__ W, int ldw, int wk0,
                                       int ksteps, int n0, const float* __restrict__ bias,
                                       float* __restrict__ C, int ldc) {
  const int l = threadIdx.x & 63;
  const int r16 = l & 15, q16 = l >> 4;
  f32x4 acc[4];
#pragma unroll
  for (int t = 0; t < 4; ++t) acc[t] = (f32x4){0.f, 0.f, 0.f, 0.f};

  const float* wp = W + (size_t)(n0 + r16) * ldw + wk0 + q16 * 8;
  const short* xh[4];
  const short* xl[4];
#pragma unroll
  for (int t = 0; t < 4; ++t) {
    int row = t * 16 + r16;
    xh[t] = Xhi + (size_t)row * ldx + xk0 + q16 * 8;
    xl[t] = Xlo + (size_t)row * ldx + xk0 + q16 * 8;
  }

  for (int ks = 0; ks < ksteps; ++ks) {
    const int ko = ks * 32;
    float4 w0 = *reinterpret_cast<const float4*>(wp + ko);
    float4 w1 = *reinterpret_cast<const float4*>(wp + ko + 4);
    short8 whi, wlo;
    hilo8(w0, w1, whi, wlo);
#pragma unroll
    for (int t = 0; t < 4; ++t) {
      short8 ah = *reinterpret_cast<const short8*>(xh[t] + ko);
      short8 al = *reinterpret_cast<const short8*>(xl[t] + ko);
      acc[t] = __builtin_amdgcn_mfma_f32_16x16x32_bf16(ah, whi, acc[t], 0, 0, 0);
      acc[t] = __builtin_amdgcn_mfma_f32_16x16x32_bf16(al, whi, acc[t], 0, 0, 0);
      acc[t] = __builtin_amdgcn_mfma_f32_16x16x32_bf16(ah, wlo, acc[t], 0, 0, 0);
    }
  }
  float bv = bias ? bias[n0 + r16] : 0.f;
#pragma unroll
  for (int t = 0; t < 4; ++t) {
#pragma unroll
    for (int r = 0; r < 4; ++r) {
      int row = t * 16 + q16 * 4 + r;
      C[(size_t)row * ldc + n0 + r16] = acc[t][r] + bv;
    }
  }
}

// ---- embed gather: cc[b][0:256] (fp32 + hi/lo) ----
__global__ void k_embed(const int* __restrict__ tok, const float* __restrict__ emb,
                        float* __restrict__ cc, short* __restrict__ cch,
                        short* __restrict__ ccl) {
  int b = blockIdx.x, t = threadIdx.x;  // 64 threads
  int token = tok[b];
  float4 v = *reinterpret_cast<const float4*>(&emb[token * E + t * 4]);
  *reinterpret_cast<float4*>(&cc[b * CCAT + t * 4]) = v;
  float f[4] = {v.x, v.y, v.z, v.w};
#pragma unroll
  for (int i = 0; i < 4; ++i)
    hilo1(f[i], &cch[b * CCAT + t * 4 + i], &ccl[b * CCAT + t * 4 + i]);
}

// ---- prevh -> h hi/lo bf16 [64][512] ----
__global__ void k_prep_h(const float* __restrict__ prevh, short* __restrict__ hh,
                         short* __restrict__ hl) {
  int idx = blockIdx.x * 256 + threadIdx.x;  // 32768
  hilo1(prevh[idx], &hh[idx], &hl[idx]);
}

// ---- q = prevh @ Wq^T, 2 K-chunks -> qpart[2][64][512] ----
__global__ void __launch_bounds__(256) k_gemm_q(const short* __restrict__ hh,
                                                const short* __restrict__ hl,
                                                const float* __restrict__ Wq,
                                                float* __restrict__ qpart) {
  int w = blockIdx.x * 4 + (threadIdx.x >> 6);  // 0..63
  int c = w >> 5, nt = w & 31;
  gemm16(hh, hl, H, c * 256, Wq, H, c * 256, 8, nt * 16, nullptr,
         qpart + (size_t)c * 64 * H, H);
}

// ---- scores[s][b] = sum_h tanh(q+pk)*We ; wave per (s,b) ----
__global__ void k_scores(const float* __restrict__ qpart, const float* __restrict__ pk,
                         const float* __restrict__ We, float* __restrict__ scores) {
  int lane = threadIdx.x & 63;
  int gw = blockIdx.x * 4 + (threadIdx.x >> 6);  // 0..31999
  int s = gw >> 6, b = gw & 63;
  const float* q0 = qpart + b * H + lane * 8;
  const float* q1 = q0 + 64 * H;
  const float* kr = pk + ((size_t)s * B + b) * H + lane * 8;
  const float* er = We + lane * 8;
  float part = 0.f;
#pragma unroll
  for (int i = 0; i < 2; ++i) {
    float4 qa = *reinterpret_cast<const float4*>(q0 + i * 4);
    float4 qb = *reinterpret_cast<const float4*>(q1 + i * 4);
    float4 kv = *reinterpret_cast<const float4*>(kr + i * 4);
    float4 ev = *reinterpret_cast<const float4*>(er + i * 4);
    part += tanhf(qa.x + qb.x + kv.x) * ev.x + tanhf(qa.y + qb.y + kv.y) * ev.y +
            tanhf(qa.z + qb.z + kv.z) * ev.z + tanhf(qa.w + qb.w + kv.w) * ev.w;
  }
  part = wsum(part);
  if (lane == 0) scores[s * B + b] = part;
}

// ---- column softmax over s; write alphas[S][B] and alphasT[B][S] ----
__global__ void k_softmax_s(const float* __restrict__ scores, float* __restrict__ alphas,
                            float* __restrict__ alphasT) {
  int b = blockIdx.x, t = threadIdx.x;  // 512 threads
  int w = t >> 6, lane = t & 63;
  __shared__ float rm[8], rl[8];
  float v = (t < S) ? scores[t * B + b] : -INFINITY;
  float m = v;
#pragma unroll
  for (int off = 32; off > 0; off >>= 1) m = fmaxf(m, __shfl_xor(m, off, 64));
  if (lane == 0) rm[w] = m;
  __syncthreads();
  float bm = rm[0];
#pragma unroll
  for (int i = 1; i < 8; ++i) bm = fmaxf(bm, rm[i]);
  float e = (t < S) ? __expf(v - bm) : 0.f;
  float sw = wsum(e);
  if (lane == 0) rl[w] = sw;
  __syncthreads();
  float tot = rl[0];
#pragma unroll
  for (int i = 1; i < 8; ++i) tot += rl[i];
  if (t < S) {
    float a = e / tot;
    alphas[t * B + b] = a;
    alphasT[b * S + t] = a;
  }
}

// ---- fused context: cc[b][768+col] = sum_s alphas[s][b]*ench[s][b][col] ----
__global__ void k_ctx(const float* __restrict__ alphasT, const float* __restrict__ ench,
                      float* __restrict__ cc, short* __restrict__ cch,
                      short* __restrict__ ccl) {
  int b = blockIdx.x >> 2, qd = blockIdx.x & 3;  // quarter of the 1024 cols
  int t = threadIdx.x;                           // 256
  __shared__ float sa[S];
  for (int i = t; i < S; i += 256) sa[i] = alphasT[b * S + i];
  __syncthreads();
  const float* base = ench + (size_t)b * 1024 + qd * 256 + t;
  float a0 = 0.f, a1 = 0.f;
#pragma unroll 8
  for (int s = 0; s < S; s += 2) {
    a0 += sa[s] * base[(size_t)s * B * 1024];
    a1 += sa[s + 1] * base[(size_t)(s + 1) * B * 1024];
  }
  float acc = a0 + a1;
  int col = 768 + qd * 256 + t;
  cc[b * CCAT + col] = acc;
  hilo1(acc, &cch[b * CCAT + col], &ccl[b * CCAT + col]);
}

// ---- GRU gemms: gi (5 chunks: embed + 4 ctx) and gh (2 chunks) partials ----
__global__ void __launch_bounds__(256) k_gemm_gru(
    const short* __restrict__ cch, const short* __restrict__ ccl,
    const short* __restrict__ hh, const short* __restrict__ hl,
    const float* __restrict__ Wih, const float* __restrict__ Whh,
    float* __restrict__ gip, float* __restrict__ ghp) {
  int w = blockIdx.x * 4 + (threadIdx.x >> 6);  // 0..671
  if (w < 480) {
    int c = w / 96, nt = w % 96;
    int xk0 = (c == 0) ? 0 : 768 + (c - 1) * 256;
    int wk0 = c * 256;
    gemm16(cch, ccl, CCAT, xk0, Wih, 1280, wk0, 8, nt * 16, nullptr,
           gip + (size_t)c * 64 * G3, G3);
  } else {
    int w2 = w - 480;
    int c = w2 / 96, nt = w2 % 96;
    gemm16(hh, hl, H, c * 256, Whh, H, c * 256, 8, nt * 16, nullptr,
           ghp + (size_t)c * 64 * G3, G3);
  }
}

// ---- GRU gates: sum partials + bias -> h_new (out, cc fp32, cc hi/lo) ----
__global__ void k_gates(const float* __restrict__ gip, const float* __restrict__ ghp,
                        const float* __restrict__ bih, const float* __restrict__ bhh,
                        const float* __restrict__ prevh, float* __restrict__ cc,
                        short* __restrict__ cch, short* __restrict__ ccl,
                        float* __restrict__ hout) {
  int idx = blockIdx.x * 256 + threadIdx.x;  // 32768
  int b = idx >> 9, j = idx & 511;
  float ir = bih[j], iz = bih[512 + j], in_ = bih[1024 + j];
#pragma unroll
  for (int c = 0; c < 5; ++c) {
    const float* g = gip + (size_t)c * 64 * G3 + b * G3;
    ir += g[j]; iz += g[512 + j]; in_ += g[1024 + j];
  }
  float hr = bhh[j], hz = bhh[512 + j], hn = bhh[1024 + j];
#pragma unroll
  for (int c = 0; c < 2; ++c) {
    const float* g = ghp + (size_t)c * 64 * G3 + b * G3;
    hr += g[j]; hz += g[512 + j]; hn += g[1024 + j];
  }
  float r = sigmoidf(ir + hr);
  float z = sigmoidf(iz + hz);
  float n = tanhf(in_ + r * hn);
  float h = prevh[b * H + j];
  float hnew = (1.f - z) * n + z * h;
  hout[b * H + j] = hnew;
  cc[b * CCAT + E + j] = hnew;
  hilo1(hnew, &cch[b * CCAT + E + j], &ccl[b * CCAT + E + j]);
}

// ---- p_gen pre-sigmoid: pgsum[b] = cc[b].pgW + pgb ----
__global__ void k_pg(const float* __restrict__ cc, const float* __restrict__ pgW,
                     const float* __restrict__ pgb, float* __restrict__ pgsum) {
  int b = blockIdx.x, t = threadIdx.x;  // 256
  float acc = 0.f;
  for (int k = t; k < CCAT; k += 256) acc += cc[b * CCAT + k] * pgW[k];
  acc = wsum(acc);
  __shared__ float sl[4];
  int w = t >> 6, lane = t & 63;
  if (lane == 0) sl[w] = acc;
  __syncthreads();
  if (t == 0) pgsum[b] = sl[0] + sl[1] + sl[2] + sl[3] + pgb[0];
}

// ---- lin gemm: 7 K-chunks -> linpart[7][64][512] ----
__global__ void __launch_bounds__(256) k_gemm_lin(const short* __restrict__ cch,
                                                  const short* __restrict__ ccl,
                                                  const float* __restrict__ linW,
                                                  float* __restrict__ linpart) {
  int w = blockIdx.x * 4 + (threadIdx.x >> 6);  // 0..223
  int c = w >> 5, nt = w & 31;
  gemm16(cch, ccl, CCAT, c * 256, linW, CCAT, c * 256, 8, nt * 16, nullptr,
         linpart + (size_t)c * 64 * H, H);
}

// ---- lin finalize: sum partials + bias -> lin hi/lo bf16 ----
__global__ void k_linfin(const float* __restrict__ linpart, const float* __restrict__ linb,
                         short* __restrict__ lh, short* __restrict__ ll) {
  int idx = blockIdx.x * 256 + threadIdx.x;  // 32768
  int b = idx >> 9, o = idx & 511;
  float v = linb[o];
#pragma unroll
  for (int c = 0; c < 7; ++c) v += linpart[(size_t)c * 64 * H + b * H + o];
  hilo1(v, &lh[idx], &ll[idx]);
}

// ---- logits gemm: full K=512, bias, fp32 out [64][V] ----
__global__ void __launch_bounds__(256) k_gemm_logits(const short* __restrict__ lh,
                                                     const short* __restrict__ ll,
                                                     const float* __restrict__ outW,
                                                     const float* __restrict__ outb,
                                                     float* __restrict__ logits) {
  int w = blockIdx.x * 4 + (threadIdx.x >> 6);
  if (w >= V / 16) return;  // 3125 tiles
  gemm16(lh, ll, H, 0, outW, H, 0, 16, w * 16, outb, logits, V);
}

// ---- online softmax partials over V (chunks of 5000) ----
__global__ void k_vmax(const float* __restrict__ logits, float* __restrict__ pm,
                       float* __restrict__ pl) {
  int b = blockIdx.x, c = blockIdx.y, t = threadIdx.x;
  const float* row = logits + (size_t)b * V + c * 5000;
  float m = -INFINITY, l = 0.f;
  for (int i = t; i < 1250; i += 256) {
    float4 v = *reinterpret_cast<const float4*>(&row[i * 4]);
    float mm = fmaxf(fmaxf(v.x, v.y), fmaxf(v.z, v.w));
    float nm = fmaxf(m, mm);
    l = l * __expf(m - nm) + __expf(v.x - nm) + __expf(v.y - nm) + __expf(v.z - nm) +
        __expf(v.w - nm);
    m = nm;
  }
#pragma unroll
  for (int off = 32; off > 0; off >>= 1) {
    float om = __shfl_xor(m, off, 64), ol = __shfl_xor(l, off, 64);
    smerge(m, l, om, ol);
  }
  __shared__ float sm[4], sl[4];
  int w = t >> 6, lane = t & 63;
  if (lane == 0) { sm[w] = m; sl[w] = l; }
  __syncthreads();
  if (t == 0) {
#pragma unroll
    for (int i = 1; i < 4; ++i) smerge(m, l, sm[i], sl[i]);
    pm[b * 10 + c] = m;
    pl[b * 10 + c] = l;
  }
}

// ---- ext init: d_out[b][v] = pg*softmax + 1e-12 ; OOV tail = 1e-12 ----
__global__ void k_extinit(const float* __restrict__ logits, const float* __restrict__ pm,
                          const float* __restrict__ pl, const float* __restrict__ pgsum,
                          float* __restrict__ out) {
  int b = blockIdx.x, c = blockIdx.y, t = threadIdx.x;
  float m = -INFINITY, l = 0.f;
#pragma unroll
  for (int i = 0; i < 10; ++i) smerge(m, l, pm[b * 10 + i], pl[b * 10 + i]);
  float pg = sigmoidf(pgsum[b]);
  float scale = pg / l;
  const float* lr = logits + (size_t)b * V + c * 5000;
  float* orow = out + (size_t)b * VEXT + c * 5000;
  for (int i = t; i < 2500; i += 256) {
    float2 v = *reinterpret_cast<const float2*>(&lr[i * 2]);
    float2 r;
    r.x = scale * __expf(v.x - m) + 1e-12f;
    r.y = scale * __expf(v.y - m) + 1e-12f;
    *reinterpret_cast<float2*>(&orow[i * 2]) = r;
  }
  if (c == 9 && t < OOVN) out[(size_t)b * VEXT + V + t] = 1e-12f;
}

// ---- pointer scatter ----
__global__ void k_scatter(const int* __restrict__ extv, const float* __restrict__ alphasT,
                          const float* __restrict__ pgsum, float* __restrict__ out) {
  int b = blockIdx.x, t = threadIdx.x;  // 512 threads
  if (t >= S) return;
  float pg = sigmoidf(pgsum[b]);
  float wgt = (1.f - pg) * alphasT[b * S + t];
  int idx = extv[b * S + t];
  atomicAdd(&out[(size_t)b * VEXT + idx], wgt);
}

// ---- in-place log ----
__global__ void k_log(float* __restrict__ out) {
  constexpr int n2 = B * VEXT / 2;
  float2* p = reinterpret_cast<float2*>(out);
  for (int i = blockIdx.x * blockDim.x + threadIdx.x; i < n2; i += gridDim.x * blockDim.x) {
    float2 v = p[i];
    v.x = logf(v.x);
    v.y = logf(v.y);
    p[i] = v;
  }
}
}  // namespace

extern "C" void kernel_launch(void* const* d_in, const int* in_sizes, int n_in,
                              void* d_out, int out_size, void* d_ws, size_t ws_size,
                              hipStream_t stream) {
  const int*   tok   = (const int*)d_in[0];
  const float* ench  = (const float*)d_in[1];
  const float* pk    = (const float*)d_in[2];
  const float* prevh = (const float*)d_in[4];
  const int*   extv  = (const int*)d_in[5];
  const float* emb   = (const float*)d_in[7];
  const float* Wq    = (const float*)d_in[8];
  const float* We    = (const float*)d_in[9];
  const float* Wih   = (const float*)d_in[10];
  const float* Whh   = (const float*)d_in[11];
  const float* bih   = (const float*)d_in[12];
  const float* bhh   = (const float*)d_in[13];
  const float* linW  = (const float*)d_in[14];
  const float* linb  = (const float*)d_in[15];
  const float* pgW   = (const float*)d_in[16];
  const float* pgb   = (const float*)d_in[17];
  const float* outW  = (const float*)d_in[18];
  const float* outb  = (const float*)d_in[19];

  float* out = (float*)d_out;
  float* ws = (float*)d_ws;

  float* qpart   = ws;                   // 2*64*512 = 65536
  float* scores  = qpart + 65536;        // 32000
  float* alphas  = scores + 32000;       // 32000
  float* alphasT = alphas + 32000;       // 32000
  float* cc      = alphasT + 32000;      // 64*1792 = 114688
  float* gip     = cc + 114688;          // 5*64*1536 = 491520
  float* ghp     = gip + 491520;         // 2*64*1536 = 196608
  float* linpart = ghp + 196608;         // 7*64*512 = 229376
  float* pgsum   = linpart + 229376;     // 64
  float* logits  = pgsum + 64;           // 64*50000 = 3200000
  float* pm      = logits + 3200000;     // 640
  float* pl      = pm + 640;             // 640
  short* sp      = (short*)(pl + 640);
  short* cch = sp;                 // 114688
  short* ccl = cch + 114688;       // 114688
  short* hh  = ccl + 114688;       // 32768
  short* hl  = hh + 32768;         // 32768
  short* lh  = hl + 32768;         // 32768
  short* ll  = lh + 32768;         // 32768
  float* hout = out + (size_t)B * VEXT;

  k_embed<<<dim3(B), dim3(64), 0, stream>>>(tok, emb, cc, cch, ccl);
  k_prep_h<<<dim3(128), dim3(256), 0, stream>>>(prevh, hh, hl);
  k_gemm_q<<<dim3(16), dim3(256), 0, stream>>>(hh, hl, Wq, qpart);
  k_scores<<<dim3(8000), dim3(256), 0, stream>>>(qpart, pk, We, scores);
  k_softmax_s<<<dim3(B), dim3(512), 0, stream>>>(scores, alphas, alphasT);
  k_ctx<<<dim3(256), dim3(256), 0, stream>>>(alphasT, ench, cc, cch, ccl);
  k_gemm_gru<<<dim3(168), dim3(256), 0, stream>>>(cch, ccl, hh, hl, Wih, Whh, gip, ghp);
  k_gates<<<dim3(128), dim3(256), 0, stream>>>(gip, ghp, bih, bhh, prevh, cc, cch, ccl, hout);
  k_pg<<<dim3(B), dim3(256), 0, stream>>>(cc, pgW, pgb, pgsum);
  k_gemm_lin<<<dim3(56), dim3(256), 0, stream>>>(cch, ccl, linW, linpart);
  k_linfin<<<dim3(128), dim3(256), 0, stream>>>(linpart, linb, lh, ll);
  k_gemm_logits<<<dim3(782), dim3(256), 0, stream>>>(lh, ll, outW, outb, logits);
  k_vmax<<<dim3(B, 10), dim3(256), 0, stream>>>(logits, pm, pl);
  k_extinit<<<dim3(B, 10), dim3(256), 0, stream>>>(logits, pm, pl, pgsum, out);
  k_scatter<<<dim3(B), dim3(512), 0, stream>>>(extv, alphasT, pgsum, out);
  k_log<<<dim3(2048), dim3(256), 0, stream>>>(out);
}

// Round 3
// 161.428 us; speedup vs baseline: 5.3257x; 1.3813x over previous
//
#include <hip/hip_runtime.h>
#include <hip/hip_bf16.h>
#include <math.h>

namespace {
constexpr int V = 50000, E = 256, H = 512, S = 500, B = 64, OOVN = 50;
constexpr int VEXT = V + OOVN;   // 50050
constexpr int CCAT = E + 3 * H;  // 1792  (embed | h_new | context)
constexpr int G3 = 3 * H;        // 1536

typedef __attribute__((ext_vector_type(8))) short short8;
typedef __attribute__((ext_vector_type(4))) float f32x4;

__device__ __forceinline__ float wsum(float v) {
#pragma unroll
  for (int off = 32; off > 0; off >>= 1) v += __shfl_xor(v, off, 64);
  return v;
}
__device__ __forceinline__ float sigmoidf(float x) { return 1.f / (1.f + __expf(-x)); }
__device__ __forceinline__ float fast_tanh(float x) {
  x = fminf(fmaxf(x, -15.f), 15.f);
  float e = __expf(2.f * x);
  return __fdividef(e - 1.f, e + 1.f);
}
__device__ __forceinline__ void smerge(float& m, float& l, float om, float ol) {
  float nm = fmaxf(m, om);
  l = l * __expf(m - nm) + ol * __expf(om - nm);
  m = nm;
}

__device__ __forceinline__ short bf16_rn_s(float f) {
  __hip_bfloat16 h = __float2bfloat16(f);
  return __builtin_bit_cast(short, h);
}
// split f into hi (bf16 truncate) + lo (bf16 rounded residual); f ~= hi + lo
__device__ __forceinline__ void hilo1(float f, short* hi, short* lo) {
  unsigned u = __float_as_uint(f);
  *hi = (short)(u >> 16);
  *lo = bf16_rn_s(f - __uint_as_float(u & 0xffff0000u));
}
__device__ __forceinline__ void hilo8(float4 a, float4 b, short8& hi, short8& lo) {
  float f[8] = {a.x, a.y, a.z, a.w, b.x, b.y, b.z, b.w};
#pragma unroll
  for (int i = 0; i < 8; ++i) {
    unsigned u = __float_as_uint(f[i]);
    hi[i] = (short)(u >> 16);
    lo[i] = bf16_rn_s(f[i] - __uint_as_float(u & 0xffff0000u));
  }
}

// ---- MFMA core (hi/lo accurate, compile-time K): wave computes C[0:64][n0:n0+16] ----
template <int KSTEPS>
__device__ __forceinline__ void gemm16(const short* __restrict__ Xhi,
                                       const short* __restrict__ Xlo, int ldx, int xk0,
                                       const float* __restrict__ W, int ldw, int wk0,
                                       int n0, const float* __restrict__ bias,
                                       float* __restrict__ C, int ldc) {
  const int l = threadIdx.x & 63;
  const int r16 = l & 15, q16 = l >> 4;
  f32x4 acc[4];
#pragma unroll
  for (int t = 0; t < 4; ++t) acc[t] = (f32x4){0.f, 0.f, 0.f, 0.f};

  const float* wp = W + (size_t)(n0 + r16) * ldw + wk0 + q16 * 8;
  const short* xh[4];
  const short* xl[4];
#pragma unroll
  for (int t = 0; t < 4; ++t) {
    int row = t * 16 + r16;
    xh[t] = Xhi + (size_t)row * ldx + xk0 + q16 * 8;
    xl[t] = Xlo + (size_t)row * ldx + xk0 + q16 * 8;
  }

#pragma unroll
  for (int ks = 0; ks < KSTEPS; ++ks) {
    const int ko = ks * 32;
    float4 w0 = *reinterpret_cast<const float4*>(wp + ko);
    float4 w1 = *reinterpret_cast<const float4*>(wp + ko + 4);
    short8 whi, wlo;
    hilo8(w0, w1, whi, wlo);
#pragma unroll
    for (int t = 0; t < 4; ++t) {
      short8 ah = *reinterpret_cast<const short8*>(xh[t] + ko);
      short8 al = *reinterpret_cast<const short8*>(xl[t] + ko);
      acc[t] = __builtin_amdgcn_mfma_f32_16x16x32_bf16(ah, whi, acc[t], 0, 0, 0);
      acc[t] = __builtin_amdgcn_mfma_f32_16x16x32_bf16(al, whi, acc[t], 0, 0, 0);
      acc[t] = __builtin_amdgcn_mfma_f32_16x16x32_bf16(ah, wlo, acc[t], 0, 0, 0);
    }
  }
  float bv = bias ? bias[n0 + r16] : 0.f;
#pragma unroll
  for (int t = 0; t < 4; ++t) {
#pragma unroll
    for (int r = 0; r < 4; ++r) {
      int row = t * 16 + q16 * 4 + r;
      C[(size_t)row * ldc + n0 + r16] = acc[t][r] + bv;
    }
  }
}

// ---- prep: h hi/lo split + embed gather ----
__global__ void k_prep(const int* __restrict__ tok, const float* __restrict__ emb,
                       const float* __restrict__ prevh, float* __restrict__ cc,
                       short* __restrict__ cch, short* __restrict__ ccl,
                       short* __restrict__ hh, short* __restrict__ hl) {
  int i = blockIdx.x * 256 + threadIdx.x;  // 32768
  hilo1(prevh[i], &hh[i], &hl[i]);
  if (i < 16384) {
    int b = i >> 8, e = i & 255;
    float v = emb[(size_t)tok[b] * E + e];
    cc[b * CCAT + e] = v;
    hilo1(v, &cch[b * CCAT + e], &ccl[b * CCAT + e]);
  }
}

// ---- q = prevh @ Wq^T, 2 K-chunks -> qpart[2][64][512] ----
__global__ void __launch_bounds__(256) k_gemm_q(const short* __restrict__ hh,
                                                const short* __restrict__ hl,
                                                const float* __restrict__ Wq,
                                                float* __restrict__ qpart) {
  int w = blockIdx.x * 4 + (threadIdx.x >> 6);  // 0..63
  int c = w >> 5, nt = w & 31;
  gemm16<8>(hh, hl, H, c * 256, Wq, H, c * 256, nt * 16, nullptr,
            qpart + (size_t)c * 64 * H, H);
}

// ---- scores[s][b] = sum_h tanh(q+pk)*We ; wave per (s,b) ----
__global__ void k_scores(const float* __restrict__ qpart, const float* __restrict__ pk,
                         const float* __restrict__ We, float* __restrict__ scores) {
  int lane = threadIdx.x & 63;
  int gw = blockIdx.x * 4 + (threadIdx.x >> 6);  // 0..31999
  int s = gw >> 6, b = gw & 63;
  const float* q0 = qpart + b * H + lane * 8;
  const float* q1 = q0 + 64 * H;
  const float* kr = pk + ((size_t)s * B + b) * H + lane * 8;
  const float* er = We + lane * 8;
  float part = 0.f;
#pragma unroll
  for (int i = 0; i < 2; ++i) {
    float4 qa = *reinterpret_cast<const float4*>(q0 + i * 4);
    float4 qb = *reinterpret_cast<const float4*>(q1 + i * 4);
    float4 kv = *reinterpret_cast<const float4*>(kr + i * 4);
    float4 ev = *reinterpret_cast<const float4*>(er + i * 4);
    part += fast_tanh(qa.x + qb.x + kv.x) * ev.x + fast_tanh(qa.y + qb.y + kv.y) * ev.y +
            fast_tanh(qa.z + qb.z + kv.z) * ev.z + fast_tanh(qa.w + qb.w + kv.w) * ev.w;
  }
  part = wsum(part);
  if (lane == 0) scores[s * B + b] = part;
}

// ---- column softmax over s -> alphasT[B][S] ----
__global__ void k_softmax_s(const float* __restrict__ scores, float* __restrict__ alphasT) {
  int b = blockIdx.x, t = threadIdx.x;  // 512 threads
  int w = t >> 6, lane = t & 63;
  __shared__ float rm[8], rl[8];
  float v = (t < S) ? scores[t * B + b] : -INFINITY;
  float m = v;
#pragma unroll
  for (int off = 32; off > 0; off >>= 1) m = fmaxf(m, __shfl_xor(m, off, 64));
  if (lane == 0) rm[w] = m;
  __syncthreads();
  float bm = rm[0];
#pragma unroll
  for (int i = 1; i < 8; ++i) bm = fmaxf(bm, rm[i]);
  float e = (t < S) ? __expf(v - bm) : 0.f;
  float sw = wsum(e);
  if (lane == 0) rl[w] = sw;
  __syncthreads();
  float tot = rl[0];
#pragma unroll
  for (int i = 1; i < 8; ++i) tot += rl[i];
  if (t < S) alphasT[b * S + t] = e / tot;
}

// ---- context partials over s-halves: ctxp[sh][b][1024] ----
__global__ void k_ctx(const float* __restrict__ alphasT, const float* __restrict__ ench,
                      float* __restrict__ ctxp) {
  int b = blockIdx.x, chf = blockIdx.y, sh = blockIdx.z;
  int t = threadIdx.x;  // 512
  __shared__ float sa[250];
  if (t < 250) sa[t] = alphasT[b * S + sh * 250 + t];
  __syncthreads();
  const float* base = ench + ((size_t)(sh * 250) * B + b) * 1024 + chf * 512 + t;
  float a0 = 0.f, a1 = 0.f;
#pragma unroll 8
  for (int s = 0; s < 250; s += 2) {
    a0 += sa[s] * base[(size_t)s * (B * 1024)];
    a1 += sa[s + 1] * base[(size_t)(s + 1) * (B * 1024)];
  }
  ctxp[((sh * B + b) * 1024) + chf * 512 + t] = a0 + a1;
}

// ---- combine ctx partials -> cc[b][768:1792] + hi/lo ----
__global__ void k_ctx2(const float* __restrict__ ctxp, float* __restrict__ cc,
                       short* __restrict__ cch, short* __restrict__ ccl) {
  int b = blockIdx.x, t = threadIdx.x;  // 64 x 256
  int c = t * 4;
  float4 v0 = *reinterpret_cast<const float4*>(&ctxp[(b * 1024) + c]);
  float4 v1 = *reinterpret_cast<const float4*>(&ctxp[((B + b) * 1024) + c]);
  float r[4] = {v0.x + v1.x, v0.y + v1.y, v0.z + v1.z, v0.w + v1.w};
#pragma unroll
  for (int i = 0; i < 4; ++i) {
    int col = 768 + c + i;
    cc[b * CCAT + col] = r[i];
    hilo1(r[i], &cch[b * CCAT + col], &ccl[b * CCAT + col]);
  }
}

// ---- GRU gemms: gi (5 chunks) and gh (2 chunks) partials ----
__global__ void __launch_bounds__(256) k_gemm_gru(
    const short* __restrict__ cch, const short* __restrict__ ccl,
    const short* __restrict__ hh, const short* __restrict__ hl,
    const float* __restrict__ Wih, const float* __restrict__ Whh,
    float* __restrict__ gip, float* __restrict__ ghp) {
  int w = blockIdx.x * 4 + (threadIdx.x >> 6);  // 0..671
  if (w < 480) {
    int c = w / 96, nt = w % 96;
    int xk0 = (c == 0) ? 0 : 768 + (c - 1) * 256;
    int wk0 = c * 256;
    gemm16<8>(cch, ccl, CCAT, xk0, Wih, 1280, wk0, nt * 16, nullptr,
              gip + (size_t)c * 64 * G3, G3);
  } else {
    int w2 = w - 480;
    int c = w2 / 96, nt = w2 % 96;
    gemm16<8>(hh, hl, H, c * 256, Whh, H, c * 256, nt * 16, nullptr,
              ghp + (size_t)c * 64 * G3, G3);
  }
}

// ---- GRU gates + p_gen (fused): block per b, 512 threads ----
__global__ void k_gates(const float* __restrict__ gip, const float* __restrict__ ghp,
                        const float* __restrict__ bih, const float* __restrict__ bhh,
                        const float* __restrict__ prevh, const float* __restrict__ pgW,
                        const float* __restrict__ pgb, float* __restrict__ cc,
                        short* __restrict__ cch, short* __restrict__ ccl,
                        float* __restrict__ hout, float* __restrict__ pgsum) {
  int b = blockIdx.x, j = threadIdx.x;  // 64 x 512
  float ir = bih[j], iz = bih[512 + j], in_ = bih[1024 + j];
#pragma unroll
  for (int c = 0; c < 5; ++c) {
    const float* g = gip + (size_t)c * 64 * G3 + b * G3;
    ir += g[j]; iz += g[512 + j]; in_ += g[1024 + j];
  }
  float hr = bhh[j], hz = bhh[512 + j], hn = bhh[1024 + j];
#pragma unroll
  for (int c = 0; c < 2; ++c) {
    const float* g = ghp + (size_t)c * 64 * G3 + b * G3;
    hr += g[j]; hz += g[512 + j]; hn += g[1024 + j];
  }
  float r = sigmoidf(ir + hr);
  float z = sigmoidf(iz + hz);
  float n = fast_tanh(in_ + r * hn);
  float h = prevh[b * H + j];
  float hnew = (1.f - z) * n + z * h;
  hout[b * H + j] = hnew;
  cc[b * CCAT + E + j] = hnew;
  hilo1(hnew, &cch[b * CCAT + E + j], &ccl[b * CCAT + E + j]);
  // p_gen partial dot
  float acc = hnew * pgW[E + j];
  acc += cc[b * CCAT + 768 + j] * pgW[768 + j];
  acc += cc[b * CCAT + 1280 + j] * pgW[1280 + j];
  if (j < 256) acc += cc[b * CCAT + j] * pgW[j];
  acc = wsum(acc);
  __shared__ float sl[8];
  int w = j >> 6, lane = j & 63;
  if (lane == 0) sl[w] = acc;
  __syncthreads();
  if (j == 0) {
    float tot = pgb[0];
#pragma unroll
    for (int i = 0; i < 8; ++i) tot += sl[i];
    pgsum[b] = tot;
  }
}

// ---- lin gemm: 7 K-chunks -> linpart[7][64][512] ----
__global__ void __launch_bounds__(256) k_gemm_lin(const short* __restrict__ cch,
                                                  const short* __restrict__ ccl,
                                                  const float* __restrict__ linW,
                                                  float* __restrict__ linpart) {
  int w = blockIdx.x * 4 + (threadIdx.x >> 6);  // 0..223
  int c = w >> 5, nt = w & 31;
  gemm16<8>(cch, ccl, CCAT, c * 256, linW, CCAT, c * 256, nt * 16, nullptr,
            linpart + (size_t)c * 64 * H, H);
}

// ---- lin finalize: sum partials + bias -> lin bf16 (hi only) ----
__global__ void k_linfin(const float* __restrict__ linpart, const float* __restrict__ linb,
                         short* __restrict__ lh) {
  int idx = blockIdx.x * 256 + threadIdx.x;  // 32768
  int b = idx >> 9, o = idx & 511;
  float v = linb[o];
#pragma unroll
  for (int c = 0; c < 7; ++c) v += linpart[(size_t)c * 64 * H + b * H + o];
  lh[idx] = bf16_rn_s(v);
}

// ---- logits gemm: LDS-staged activations, bf16 weights, 1 tile/wave ----
__global__ void __launch_bounds__(512, 4) k_gemm_logits(
    const short* __restrict__ lh, const float* __restrict__ outW,
    const float* __restrict__ outb, float* __restrict__ logits) {
  __shared__ __align__(16) short xs[64 * 512];
  char* xb = reinterpret_cast<char*>(xs);
  int tid = threadIdx.x;
#pragma unroll
  for (int k = 0; k < 8; ++k) {
    int m = k * 512 + tid;  // 16B chunk id, 4096 total
    int row = m >> 6;
    short8 v = *reinterpret_cast<const short8*>(lh + (size_t)m * 8);
    int byte = (m * 16) ^ ((row & 7) << 4);
    *reinterpret_cast<short8*>(xb + byte) = v;
  }
  __syncthreads();
  const int l = tid & 63;
  const int r16 = l & 15, q16 = l >> 4;
  const int waveId = blockIdx.x * 8 + (tid >> 6);
  if (waveId >= V / 16) return;  // 3125 tiles
  const int n0 = waveId * 16;
  f32x4 acc[4];
#pragma unroll
  for (int t = 0; t < 4; ++t) acc[t] = (f32x4){0.f, 0.f, 0.f, 0.f};
  const float* wp = outW + (size_t)(n0 + r16) * H + q16 * 8;
  int arow[4], aswz[4];
#pragma unroll
  for (int t = 0; t < 4; ++t) {
    int row = t * 16 + r16;
    arow[t] = row * 1024 + q16 * 16;
    aswz[t] = (row & 7) << 4;
  }
#pragma unroll
  for (int ks = 0; ks < 16; ++ks) {
    float4 w0 = *reinterpret_cast<const float4*>(wp + ks * 32);
    float4 w1 = *reinterpret_cast<const float4*>(wp + ks * 32 + 4);
    short8 wh;
    wh[0] = bf16_rn_s(w0.x); wh[1] = bf16_rn_s(w0.y);
    wh[2] = bf16_rn_s(w0.z); wh[3] = bf16_rn_s(w0.w);
    wh[4] = bf16_rn_s(w1.x); wh[5] = bf16_rn_s(w1.y);
    wh[6] = bf16_rn_s(w1.z); wh[7] = bf16_rn_s(w1.w);
#pragma unroll
    for (int t = 0; t < 4; ++t) {
      short8 a = *reinterpret_cast<const short8*>(xb + ((arow[t] + ks * 64) ^ aswz[t]));
      acc[t] = __builtin_amdgcn_mfma_f32_16x16x32_bf16(a, wh, acc[t], 0, 0, 0);
    }
  }
  float bv = outb[n0 + r16];
#pragma unroll
  for (int t = 0; t < 4; ++t) {
#pragma unroll
    for (int r = 0; r < 4; ++r) {
      int row = t * 16 + q16 * 4 + r;
      logits[(size_t)row * V + n0 + r16] = acc[t][r] + bv;
    }
  }
}

// ---- online softmax partials over V (chunks of 5000) ----
__global__ void k_vmax(const float* __restrict__ logits, float* __restrict__ pm,
                       float* __restrict__ pl) {
  int b = blockIdx.x, c = blockIdx.y, t = threadIdx.x;
  const float* row = logits + (size_t)b * V + c * 5000;
  float m = -INFINITY, l = 0.f;
  for (int i = t; i < 1250; i += 256) {
    float4 v = *reinterpret_cast<const float4*>(&row[i * 4]);
    float mm = fmaxf(fmaxf(v.x, v.y), fmaxf(v.z, v.w));
    float nm = fmaxf(m, mm);
    l = l * __expf(m - nm) + __expf(v.x - nm) + __expf(v.y - nm) + __expf(v.z - nm) +
        __expf(v.w - nm);
    m = nm;
  }
#pragma unroll
  for (int off = 32; off > 0; off >>= 1) {
    float om = __shfl_xor(m, off, 64), ol = __shfl_xor(l, off, 64);
    smerge(m, l, om, ol);
  }
  __shared__ float sm[4], sl[4];
  int w = t >> 6, lane = t & 63;
  if (lane == 0) { sm[w] = m; sl[w] = l; }
  __syncthreads();
  if (t == 0) {
#pragma unroll
    for (int i = 1; i < 4; ++i) smerge(m, l, sm[i], sl[i]);
    pm[b * 10 + c] = m;
    pl[b * 10 + c] = l;
  }
}

// ---- ext init: d_out[b][v] = pg*softmax + 1e-12 ; OOV tail = 1e-12 ----
__global__ void k_extinit(const float* __restrict__ logits, const float* __restrict__ pm,
                          const float* __restrict__ pl, const float* __restrict__ pgsum,
                          float* __restrict__ out) {
  int b = blockIdx.x, c = blockIdx.y, t = threadIdx.x;
  float m = -INFINITY, l = 0.f;
#pragma unroll
  for (int i = 0; i < 10; ++i) smerge(m, l, pm[b * 10 + i], pl[b * 10 + i]);
  float pg = sigmoidf(pgsum[b]);
  float scale = pg / l;
  const float* lr = logits + (size_t)b * V + c * 5000;
  float* orow = out + (size_t)b * VEXT + c * 5000;
  for (int i = t; i < 2500; i += 256) {
    float2 v = *reinterpret_cast<const float2*>(&lr[i * 2]);
    float2 r;
    r.x = scale * __expf(v.x - m) + 1e-12f;
    r.y = scale * __expf(v.y - m) + 1e-12f;
    *reinterpret_cast<float2*>(&orow[i * 2]) = r;
  }
  if (c == 9 && t < OOVN) out[(size_t)b * VEXT + V + t] = 1e-12f;
}

// ---- pointer scatter + log, fused per row-quarter ----
__constant__ int qbound[5] = {0, 12512, 25024, 37536, 50050};
__global__ void k_scatter_log(const int* __restrict__ extv, const float* __restrict__ alphasT,
                              const float* __restrict__ pgsum, float* __restrict__ out) {
  int b = blockIdx.x >> 2, q = blockIdx.x & 3, t = threadIdx.x;  // 256 blocks x 256
  int qs0 = qbound[q], qs1 = qbound[q + 1];
  float pg = sigmoidf(pgsum[b]);
  float* row = out + (size_t)b * VEXT;
  for (int s = t; s < S; s += 256) {
    int idx = extv[b * S + s];
    if (idx >= qs0 && idx < qs1) atomicAdd(&row[idx], (1.f - pg) * alphasT[b * S + s]);
  }
  __threadfence();
  __syncthreads();
  int n2 = (qs1 - qs0) >> 1;
  float2* p = reinterpret_cast<float2*>(row + qs0);
  for (int i = t; i < n2; i += 256) {
    float2 v = p[i];
    v.x = logf(v.x);
    v.y = logf(v.y);
    p[i] = v;
  }
  if (((qs1 - qs0) & 1) && t == 0) row[qs1 - 1] = logf(row[qs1 - 1]);
}
}  // namespace

extern "C" void kernel_launch(void* const* d_in, const int* in_sizes, int n_in,
                              void* d_out, int out_size, void* d_ws, size_t ws_size,
                              hipStream_t stream) {
  const int*   tok   = (const int*)d_in[0];
  const float* ench  = (const float*)d_in[1];
  const float* pk    = (const float*)d_in[2];
  const float* prevh = (const float*)d_in[4];
  const int*   extv  = (const int*)d_in[5];
  const float* emb   = (const float*)d_in[7];
  const float* Wq    = (const float*)d_in[8];
  const float* We    = (const float*)d_in[9];
  const float* Wih   = (const float*)d_in[10];
  const float* Whh   = (const float*)d_in[11];
  const float* bih   = (const float*)d_in[12];
  const float* bhh   = (const float*)d_in[13];
  const float* linW  = (const float*)d_in[14];
  const float* linb  = (const float*)d_in[15];
  const float* pgW   = (const float*)d_in[16];
  const float* pgb   = (const float*)d_in[17];
  const float* outW  = (const float*)d_in[18];
  const float* outb  = (const float*)d_in[19];

  float* out = (float*)d_out;
  float* ws = (float*)d_ws;

  float* qpart   = ws;                   // 2*64*512 = 65536
  float* scores  = qpart + 65536;        // 32000
  float* alphasT = scores + 32000;       // 32000
  float* ctxp    = alphasT + 32000;      // 2*64*1024 = 131072
  float* cc      = ctxp + 131072;        // 64*1792 = 114688
  float* gip     = cc + 114688;          // 5*64*1536 = 491520
  float* ghp     = gip + 491520;         // 2*64*1536 = 196608
  float* linpart = ghp + 196608;         // 7*64*512 = 229376
  float* pgsum   = linpart + 229376;     // 64
  float* logits  = pgsum + 64;           // 64*50000 = 3200000
  float* pm      = logits + 3200000;     // 640
  float* pl      = pm + 640;             // 640
  short* sp      = (short*)(pl + 640);
  short* cch = sp;                 // 114688
  short* ccl = cch + 114688;       // 114688
  short* hh  = ccl + 114688;       // 32768
  short* hl  = hh + 32768;         // 32768
  short* lh  = hl + 32768;         // 32768
  float* hout = out + (size_t)B * VEXT;

  k_prep<<<dim3(128), dim3(256), 0, stream>>>(tok, emb, prevh, cc, cch, ccl, hh, hl);
  k_gemm_q<<<dim3(16), dim3(256), 0, stream>>>(hh, hl, Wq, qpart);
  k_scores<<<dim3(8000), dim3(256), 0, stream>>>(qpart, pk, We, scores);
  k_softmax_s<<<dim3(B), dim3(512), 0, stream>>>(scores, alphasT);
  k_ctx<<<dim3(64, 2, 2), dim3(512), 0, stream>>>(alphasT, ench, ctxp);
  k_ctx2<<<dim3(B), dim3(256), 0, stream>>>(ctxp, cc, cch, ccl);
  k_gemm_gru<<<dim3(168), dim3(256), 0, stream>>>(cch, ccl, hh, hl, Wih, Whh, gip, ghp);
  k_gates<<<dim3(B), dim3(512), 0, stream>>>(gip, ghp, bih, bhh, prevh, pgW, pgb, cc, cch,
                                             ccl, hout, pgsum);
  k_gemm_lin<<<dim3(56), dim3(256), 0, stream>>>(cch, ccl, linW, linpart);
  k_linfin<<<dim3(128), dim3(256), 0, stream>>>(linpart, linb, lh);
  k_gemm_logits<<<dim3(391), dim3(512), 0, stream>>>(lh, outW, outb, logits);
  k_vmax<<<dim3(B, 10), dim3(256), 0, stream>>>(logits, pm, pl);
  k_extinit<<<dim3(B, 10), dim3(256), 0, stream>>>(logits, pm, pl, pgsum, out);
  k_scatter_log<<<dim3(256), dim3(256), 0, stream>>>(extv, alphasT, pgsum, out);
}